// Round 8
// baseline (409.540 us; speedup 1.0000x reference)
//
#include <hip/hip_runtime.h>

#define NN 100000
#define NE 1600000
#define SH 7
#define NB_BKT 782        // ceil(100000/128)
#define CHUNK 8192

static inline int cdiv(long long a, int b) { return (int)((a + b - 1) / b); }

// ======================= bucketed CSR build ==============================
__global__ void bucket_hist(const int* __restrict__ col, int* __restrict__ bcnt, int E) {
    __shared__ int lh[NB_BKT];
    for (int i = threadIdx.x; i < NB_BKT; i += 256) lh[i] = 0;
    __syncthreads();
    int base = blockIdx.x * CHUNK;
    int end = min(base + CHUNK, E);
    for (int e = base + threadIdx.x; e < end; e += 256) atomicAdd(&lh[col[e] >> SH], 1);
    __syncthreads();
    for (int i = threadIdx.x; i < NB_BKT; i += 256)
        if (lh[i]) atomicAdd(&bcnt[i], lh[i]);
}

__global__ void bucket_scan(const int* __restrict__ bcnt, int* __restrict__ bptr,
                            int* __restrict__ bcur) {
    int t = threadIdx.x;
    int v[4];
    int base = 4 * t;
    int s = 0;
#pragma unroll
    for (int c = 0; c < 4; c++) {
        int i = base + c;
        v[c] = (i < NB_BKT) ? bcnt[i] : 0;
        s += v[c];
    }
    int lane = t & 63, wv = t >> 6;
    int incl = s;
#pragma unroll
    for (int off = 1; off < 64; off <<= 1) {
        int u = __shfl_up(incl, off, 64);
        if (lane >= off) incl += u;
    }
    __shared__ int wtot[4];
    if (lane == 63) wtot[wv] = incl;
    __syncthreads();
    int woff = 0;
    for (int w = 0; w < wv; w++) woff += wtot[w];
    int excl = woff + incl - s;
#pragma unroll
    for (int c = 0; c < 4; c++) {
        int i = base + c;
        if (i < NB_BKT) { bptr[i] = excl; bcur[i] = excl; }
        excl += v[c];
    }
    if (t == 255) bptr[NB_BKT] = woff + incl;
}

__global__ void partition_kernel(const int* __restrict__ row, const int* __restrict__ col,
                                 int* __restrict__ bcur,
                                 unsigned long long* __restrict__ packed, int E) {
    __shared__ int lh[NB_BKT];
    __shared__ int lbase[NB_BKT];
    for (int i = threadIdx.x; i < NB_BKT; i += 256) lh[i] = 0;
    __syncthreads();
    int base = blockIdx.x * CHUNK;
    int end = min(base + CHUNK, E);
    for (int e = base + threadIdx.x; e < end; e += 256) atomicAdd(&lh[col[e] >> SH], 1);
    __syncthreads();
    for (int i = threadIdx.x; i < NB_BKT; i += 256) {
        int v = lh[i];
        lbase[i] = v ? atomicAdd(&bcur[i], v) : 0;
        lh[i] = 0;
    }
    __syncthreads();
    for (int e = base + threadIdx.x; e < end; e += 256) {
        int c = col[e];
        int r = row[e];
        int b = c >> SH;
        int off = atomicAdd(&lh[b], 1);
        packed[lbase[b] + off] = ((unsigned long long)(unsigned)c << 32) | (unsigned)r;
    }
}

// Per-bucket: degree count -> in-block scan -> rowptr, self-edge, dinv.
// rowptr[node] = bptr[b] + 128*b + prefix(cnt+1 within bucket)
__global__ void bucket_nodes(const unsigned long long* __restrict__ packed,
                             const int* __restrict__ bptr, int* __restrict__ rowptr,
                             float* __restrict__ dinv, int* __restrict__ csr_row, int N) {
    int b = blockIdx.x;
    __shared__ int lcnt[128];
    __shared__ int wt4[4];
    int t = threadIdx.x;
    if (t < 128) lcnt[t] = 0;
    __syncthreads();
    int s = bptr[b], e = bptr[b + 1];
    for (int i = s + t; i < e; i += 256)
        atomicAdd(&lcnt[(int)(packed[i] >> 32) & 127], 1);
    __syncthreads();
    int node = (b << SH) + t;
    int v = (t < 128 && node < N) ? lcnt[t] + 1 : 0;   // +1 = self-edge slot
    int lane = t & 63, w = t >> 6;
    int incl = v;
#pragma unroll
    for (int off = 1; off < 64; off <<= 1) {
        int u = __shfl_up(incl, off, 64);
        if (lane >= off) incl += u;
    }
    if (lane == 63) wt4[w] = incl;
    __syncthreads();
    int woff = 0;
    for (int i = 0; i < w; i++) woff += wt4[i];
    int excl = woff + incl - v;
    if (t < 128 && node < N) {
        int start = bptr[b] + (b << SH) + excl;
        rowptr[node] = start;
        csr_row[start] = node;       // self edge first in segment
        dinv[node] = rsqrtf((float)v);
    }
    if (b == 0 && t == 0) rowptr[N] = NE + NN;
}

__global__ void bucket_place(const unsigned long long* __restrict__ packed,
                             const int* __restrict__ bptr, const int* __restrict__ rowptr,
                             int* __restrict__ csr_row, int N) {
    int b = blockIdx.x;
    __shared__ int lcur[128];
    int node = (b << SH) + threadIdx.x;
    if (threadIdx.x < 128 && node < N) lcur[threadIdx.x] = rowptr[node] + 1;
    __syncthreads();
    int s = bptr[b], e = bptr[b + 1];
    for (int i = s + threadIdx.x; i < e; i += 256) {
        unsigned long long p = packed[i];
        int c = (int)(p >> 32);
        int r = (int)(p & 0xffffffffu);
        int pos = atomicAdd(&lcur[c & 127], 1);
        csr_row[pos] = r;
    }
}

// ======================= x pad copy (21 -> stride 32, zero pad) ==========
__global__ void padx_kernel(const float* __restrict__ x, float* __restrict__ xp, int N) {
    int idx = blockIdx.x * blockDim.x + threadIdx.x;
    if (idx >= N * 32) return;
    int n = idx >> 5;
    int k = idx & 31;
    xp[idx] = (k < 21) ? x[n * 21 + k] : 0.f;
}

// ======================= fused gather + GEMM (L1, L2) ====================
// Bank-check: L1 (JG=8,RJ=4) spans 16 banks/k -> conflict-free; L2 (JG=8,RJ=8)
// -> 2-way on Ws b128 = free (m136).
template <int LPN, int FIN, int FOUT, int RJ, int OSTRIDE>
__global__ __launch_bounds__(512) void gather_gemm(
    const float4* __restrict__ h, const int* __restrict__ rowptr,
    const int* __restrict__ csr_row, const float* __restrict__ dinv,
    const float* __restrict__ W, const float* __restrict__ b,
    float* __restrict__ out, int N) {
    constexpr int NT = 512 / LPN;        // nodes per block
    constexpr int FINP = 4 * LPN;        // gathered row width (>= FIN)
    constexpr int XLD = FINP + 1;
    constexpr int JG = FOUT / RJ;        // must satisfy 512/JG == NT
    __shared__ float xs[NT * XLD];
    __shared__ float Ws[FIN * FOUT];
    __shared__ float bs[FOUT];
    const int t = threadIdx.x;

    for (int i = t; i < FIN * FOUT; i += 512) Ws[i] = W[i];
    if (t < FOUT) bs[t] = b[t];

    // ---- gather phase ----
    const int l = t % LPN;
    const int ny = t / LPN;
    const int node = blockIdx.x * NT + ny;
    float4 acc = make_float4(0.f, 0.f, 0.f, 0.f);
    if (node < N) {
        int s = rowptr[node], e = rowptr[node + 1];
        float dn = dinv[node];
        int i = s;
        for (; i + 3 < e; i += 4) {
            int r0 = csr_row[i], r1 = csr_row[i + 1], r2 = csr_row[i + 2], r3 = csr_row[i + 3];
            float w0 = dinv[r0] * dn, w1 = dinv[r1] * dn, w2 = dinv[r2] * dn, w3 = dinv[r3] * dn;
            float4 a0 = h[(size_t)r0 * LPN + l];
            float4 a1 = h[(size_t)r1 * LPN + l];
            float4 a2 = h[(size_t)r2 * LPN + l];
            float4 a3 = h[(size_t)r3 * LPN + l];
            acc.x = fmaf(w0, a0.x, acc.x); acc.y = fmaf(w0, a0.y, acc.y);
            acc.z = fmaf(w0, a0.z, acc.z); acc.w = fmaf(w0, a0.w, acc.w);
            acc.x = fmaf(w1, a1.x, acc.x); acc.y = fmaf(w1, a1.y, acc.y);
            acc.z = fmaf(w1, a1.z, acc.z); acc.w = fmaf(w1, a1.w, acc.w);
            acc.x = fmaf(w2, a2.x, acc.x); acc.y = fmaf(w2, a2.y, acc.y);
            acc.z = fmaf(w2, a2.z, acc.z); acc.w = fmaf(w2, a2.w, acc.w);
            acc.x = fmaf(w3, a3.x, acc.x); acc.y = fmaf(w3, a3.y, acc.y);
            acc.z = fmaf(w3, a3.z, acc.z); acc.w = fmaf(w3, a3.w, acc.w);
        }
        for (; i < e; i++) {
            int r0 = csr_row[i];
            float w0 = dinv[r0] * dn;
            float4 a0 = h[(size_t)r0 * LPN + l];
            acc.x = fmaf(w0, a0.x, acc.x); acc.y = fmaf(w0, a0.y, acc.y);
            acc.z = fmaf(w0, a0.z, acc.z); acc.w = fmaf(w0, a0.w, acc.w);
        }
    }
    xs[ny * XLD + 4 * l + 0] = acc.x;
    xs[ny * XLD + 4 * l + 1] = acc.y;
    xs[ny * XLD + 4 * l + 2] = acc.z;
    xs[ny * XLD + 4 * l + 3] = acc.w;
    __syncthreads();

    // ---- GEMM phase ----
    const int jg = t % JG;
    const int ng = t / JG;
    float r[RJ];
#pragma unroll
    for (int jj = 0; jj < RJ; jj++) r[jj] = 0.f;
#pragma unroll 4
    for (int k = 0; k < FIN; k++) {
        float xv = xs[ng * XLD + k];
#pragma unroll
        for (int jj = 0; jj < RJ; jj++)
            r[jj] = fmaf(xv, Ws[k * FOUT + jg * RJ + jj], r[jj]);
    }
    int onode = blockIdx.x * NT + ng;
    if (onode < N) {
        float* orow = out + (size_t)onode * OSTRIDE + jg * RJ;
#pragma unroll
        for (int jj = 0; jj < RJ; jj++) r[jj] = fmaxf(r[jj] + bs[jg * RJ + jj], 0.f);
#pragma unroll
        for (int c = 0; c < RJ / 4; c++)
            *(float4*)&orow[4 * c] = make_float4(r[4 * c], r[4 * c + 1], r[4 * c + 2], r[4 * c + 3]);
    }
}

// ======================= standalone gather ===============================
template <int LPN, bool BIAS, bool STORE21>
__global__ void gather4_kernel(const float4* __restrict__ h, const int* __restrict__ rowptr,
                               const int* __restrict__ csr_row, const float* __restrict__ dinv,
                               const float* __restrict__ bias, float* __restrict__ outp, int N) {
    int node = blockIdx.x * blockDim.y + threadIdx.y;
    if (node >= N) return;
    int l = threadIdx.x;
    int s = rowptr[node], e = rowptr[node + 1];
    float dn = dinv[node];
    float4 acc = make_float4(0.f, 0.f, 0.f, 0.f);
    int i = s;
    for (; i + 3 < e; i += 4) {
        int r0 = csr_row[i], r1 = csr_row[i + 1], r2 = csr_row[i + 2], r3 = csr_row[i + 3];
        float w0 = dinv[r0] * dn, w1 = dinv[r1] * dn, w2 = dinv[r2] * dn, w3 = dinv[r3] * dn;
        float4 a0 = h[(size_t)r0 * LPN + l];
        float4 a1 = h[(size_t)r1 * LPN + l];
        float4 a2 = h[(size_t)r2 * LPN + l];
        float4 a3 = h[(size_t)r3 * LPN + l];
        acc.x = fmaf(w0, a0.x, acc.x); acc.y = fmaf(w0, a0.y, acc.y);
        acc.z = fmaf(w0, a0.z, acc.z); acc.w = fmaf(w0, a0.w, acc.w);
        acc.x = fmaf(w1, a1.x, acc.x); acc.y = fmaf(w1, a1.y, acc.y);
        acc.z = fmaf(w1, a1.z, acc.z); acc.w = fmaf(w1, a1.w, acc.w);
        acc.x = fmaf(w2, a2.x, acc.x); acc.y = fmaf(w2, a2.y, acc.y);
        acc.z = fmaf(w2, a2.z, acc.z); acc.w = fmaf(w2, a2.w, acc.w);
        acc.x = fmaf(w3, a3.x, acc.x); acc.y = fmaf(w3, a3.y, acc.y);
        acc.z = fmaf(w3, a3.z, acc.z); acc.w = fmaf(w3, a3.w, acc.w);
    }
    for (; i < e; i++) {
        int r0 = csr_row[i];
        float w0 = dinv[r0] * dn;
        float4 a0 = h[(size_t)r0 * LPN + l];
        acc.x = fmaf(w0, a0.x, acc.x); acc.y = fmaf(w0, a0.y, acc.y);
        acc.z = fmaf(w0, a0.z, acc.z); acc.w = fmaf(w0, a0.w, acc.w);
    }
    if (STORE21) {
        int j = 4 * l;
        float v[4] = {acc.x, acc.y, acc.z, acc.w};
#pragma unroll
        for (int c = 0; c < 4; c++) {
            int jj = j + c;
            if (jj < 21) outp[(size_t)node * 21 + jj] = v[c] + (BIAS ? bias[jj] : 0.f);
        }
    } else {
        ((float4*)outp)[(size_t)node * LPN + l] = acc;
    }
}

// ======================= fused L3+L4 GEMM ================================
// in: agg3 (stride 64).  h3 = relu(agg3*W3 + b3) kept in LDS.
// out: h4 = h3*W4 (21 cols, pad 24) stored at stride 32.
// 32 nodes/block, 256 threads. LDS ~69KB -> 2 blocks/CU.
__global__ __launch_bounds__(256) void gemm_l3l4(
    const float* __restrict__ agg, const float* __restrict__ W3,
    const float* __restrict__ b3, const float* __restrict__ W4,
    float* __restrict__ out, int N) {
    __shared__ float xs[32 * 65];        // agg tile
    __shared__ float W3s[64 * 128];
    __shared__ float b3s[128];
    __shared__ float hm[32 * 129];       // h3 tile
    __shared__ float W4s[128 * 24];      // zero-padded cols 21..23
    const int t = threadIdx.x;
    const int node0 = blockIdx.x * 32;

    for (int i = t; i < 64 * 128 / 4; i += 256) ((float4*)W3s)[i] = ((const float4*)W3)[i];
    if (t < 128) b3s[t] = b3[t];
    for (int i = t; i < 128 * 24; i += 256) {
        int k = i / 24, j = i - k * 24;
        W4s[i] = (j < 21) ? W4[k * 21 + j] : 0.f;
    }
    for (int i = t; i < 32 * 16; i += 256) {   // 16 float4 per node
        int n = i >> 4, kk = i & 15;
        int node = node0 + n;
        float4 v = (node < N) ? ((const float4*)agg)[(size_t)node * 16 + kk]
                              : make_float4(0.f, 0.f, 0.f, 0.f);
        xs[n * 65 + 4 * kk + 0] = v.x;
        xs[n * 65 + 4 * kk + 1] = v.y;
        xs[n * 65 + 4 * kk + 2] = v.z;
        xs[n * 65 + 4 * kk + 3] = v.w;
    }
    __syncthreads();

    // phase 1: hm = relu(xs * W3s + b3)   (jg: 8 groups of 16 cols, ng: 32 nodes)
    {
        const int jg = t & 7;
        const int ng = t >> 3;
        float acc[16];
#pragma unroll
        for (int jj = 0; jj < 16; jj++) acc[jj] = 0.f;
#pragma unroll 2
        for (int k = 0; k < 64; k++) {
            float xv = xs[ng * 65 + k];
            const float* wr = &W3s[k * 128 + jg * 16];
#pragma unroll
            for (int c = 0; c < 4; c++) {
                float4 w = *(const float4*)&wr[4 * c];
                acc[4 * c + 0] = fmaf(xv, w.x, acc[4 * c + 0]);
                acc[4 * c + 1] = fmaf(xv, w.y, acc[4 * c + 1]);
                acc[4 * c + 2] = fmaf(xv, w.z, acc[4 * c + 2]);
                acc[4 * c + 3] = fmaf(xv, w.w, acc[4 * c + 3]);
            }
        }
        float* hr = &hm[ng * 129 + jg * 16];
#pragma unroll
        for (int jj = 0; jj < 16; jj++) hr[jj] = fmaxf(acc[jj] + b3s[jg * 16 + jj], 0.f);
    }
    __syncthreads();

    // phase 2: out = hm * W4s   (jg: 8 groups of 3 cols, ng: 32 nodes)
    {
        const int jg = t & 7;
        const int ng = t >> 3;
        float a0 = 0.f, a1 = 0.f, a2 = 0.f;
        const float* hrow = &hm[ng * 129];
#pragma unroll 4
        for (int k = 0; k < 128; k++) {
            float xv = hrow[k];
            const float* wr = &W4s[k * 24 + jg * 3];
            a0 = fmaf(xv, wr[0], a0);
            a1 = fmaf(xv, wr[1], a1);
            a2 = fmaf(xv, wr[2], a2);
        }
        int node = node0 + ng;
        if (node < N) {
            float* orow = out + (size_t)node * 32 + jg * 3;
            orow[0] = a0; orow[1] = a1; orow[2] = a2;
        }
    }
}

// ======================= launch ==========================================
extern "C" void kernel_launch(void* const* d_in, const int* in_sizes, int n_in,
                              void* d_out, int out_size, void* d_ws, size_t ws_size,
                              hipStream_t stream) {
    const float* x  = (const float*)d_in[0];
    const int*   ei = (const int*)d_in[1];
    const float* W1 = (const float*)d_in[2]; const float* b1 = (const float*)d_in[3];
    const float* W2 = (const float*)d_in[4]; const float* b2 = (const float*)d_in[5];
    const float* W3 = (const float*)d_in[6]; const float* b3 = (const float*)d_in[7];
    const float* W4 = (const float*)d_in[8]; const float* b4 = (const float*)d_in[9];
    const int* row = ei;
    const int* col = ei + NE;
    float* out = (float*)d_out;

    // workspace layout (floats)
    float* A      = (float*)d_ws;                  // N x 128
    float* B      = A + (size_t)NN * 128;          // N x 128
    float* dinv   = B + (size_t)NN * 128;          // N
    int*   rowptr = (int*)(dinv + NN);             // N+1
    int*   csr_row= rowptr + NN + 1;               // E + N
    int*   bcnt   = csr_row + NE + NN;             // NB_BKT
    int*   bptr   = bcnt + NB_BKT;                 // NB_BKT+1
    int*   bcur   = bptr + NB_BKT + 1;             // NB_BKT
    // packed (col,row) u64 aliases A: dead before layer-1 writes A
    unsigned long long* packed = (unsigned long long*)A;

    const int BS = 256;
    const int NCH = cdiv(NE, CHUNK);    // 196

    // ---- bucketed CSR build (6 dispatches) ----
    hipMemsetAsync(bcnt, 0, NB_BKT * sizeof(int), stream);
    bucket_hist<<<NCH, 256, 0, stream>>>(col, bcnt, NE);
    bucket_scan<<<1, 256, 0, stream>>>(bcnt, bptr, bcur);
    partition_kernel<<<NCH, 256, 0, stream>>>(row, col, bcur, packed, NE);
    bucket_nodes<<<NB_BKT, 256, 0, stream>>>(packed, bptr, rowptr, dinv, csr_row, NN);
    bucket_place<<<NB_BKT, 256, 0, stream>>>(packed, bptr, rowptr, csr_row, NN);

    // ---- pad x into B (stride 32, zero-padded) ----
    padx_kernel<<<cdiv((long long)NN * 32, BS), BS, 0, stream>>>(x, B, NN);

    // ---- L1: fused gather(x32)+gemm 21->32 +b relu : B -> A (stride 32) ----
    gather_gemm<8, 21, 32, 4, 32><<<cdiv(NN, 64), 512, 0, stream>>>(
        (const float4*)B, rowptr, csr_row, dinv, W1, b1, A, NN);
    // ---- L2: fused gather(h1)+gemm 32->64 +b relu : A -> B (stride 64) ----
    gather_gemm<8, 32, 64, 8, 64><<<cdiv(NN, 64), 512, 0, stream>>>(
        (const float4*)A, rowptr, csr_row, dinv, W2, b2, B, NN);
    // ---- L3 gather: B -> A (stride 64) ----
    {
        dim3 blk(16, 16);
        gather4_kernel<16, false, false><<<cdiv(NN, 16), blk, 0, stream>>>(
            (const float4*)B, rowptr, csr_row, dinv, nullptr, A, NN);
    }
    // ---- fused L3+L4 GEMM: A -> B (h4, stride 32) ----
    gemm_l3l4<<<cdiv(NN, 32), 256, 0, stream>>>(A, W3, b3, W4, B, NN);
    // ---- L4 gather + b4: B -> out (stride 21) ----
    {
        dim3 blk(8, 32);
        gather4_kernel<8, true, true><<<cdiv(NN, 32), blk, 0, stream>>>(
            (const float4*)B, rowptr, csr_row, dinv, b4, out, NN);
    }
}

// Round 9
// 372.877 us; speedup vs baseline: 1.0983x; 1.0983x over previous
//
#include <hip/hip_runtime.h>

#define NN 100000
#define NE 1600000
#define SH 7
#define NB_BKT 782        // ceil(100000/128)
#define CHUNK 8192

static inline int cdiv(long long a, int b) { return (int)((a + b - 1) / b); }

// ======================= bucketed CSR build ==============================
__global__ void bucket_hist(const int* __restrict__ col, int* __restrict__ bcnt, int E) {
    __shared__ int lh[NB_BKT];
    for (int i = threadIdx.x; i < NB_BKT; i += 256) lh[i] = 0;
    __syncthreads();
    int base = blockIdx.x * CHUNK;
    int end = min(base + CHUNK, E);
    for (int e = base + threadIdx.x; e < end; e += 256) atomicAdd(&lh[col[e] >> SH], 1);
    __syncthreads();
    for (int i = threadIdx.x; i < NB_BKT; i += 256)
        if (lh[i]) atomicAdd(&bcnt[i], lh[i]);
}

__global__ void bucket_scan(const int* __restrict__ bcnt, int* __restrict__ bptr,
                            int* __restrict__ bcur) {
    int t = threadIdx.x;
    int v[4];
    int base = 4 * t;
    int s = 0;
#pragma unroll
    for (int c = 0; c < 4; c++) {
        int i = base + c;
        v[c] = (i < NB_BKT) ? bcnt[i] : 0;
        s += v[c];
    }
    int lane = t & 63, wv = t >> 6;
    int incl = s;
#pragma unroll
    for (int off = 1; off < 64; off <<= 1) {
        int u = __shfl_up(incl, off, 64);
        if (lane >= off) incl += u;
    }
    __shared__ int wtot[4];
    if (lane == 63) wtot[wv] = incl;
    __syncthreads();
    int woff = 0;
    for (int w = 0; w < wv; w++) woff += wtot[w];
    int excl = woff + incl - s;
#pragma unroll
    for (int c = 0; c < 4; c++) {
        int i = base + c;
        if (i < NB_BKT) { bptr[i] = excl; bcur[i] = excl; }
        excl += v[c];
    }
    if (t == 255) bptr[NB_BKT] = woff + incl;
}

__global__ void partition_kernel(const int* __restrict__ row, const int* __restrict__ col,
                                 int* __restrict__ bcur,
                                 unsigned long long* __restrict__ packed, int E) {
    __shared__ int lh[NB_BKT];
    __shared__ int lbase[NB_BKT];
    for (int i = threadIdx.x; i < NB_BKT; i += 256) lh[i] = 0;
    __syncthreads();
    int base = blockIdx.x * CHUNK;
    int end = min(base + CHUNK, E);
    for (int e = base + threadIdx.x; e < end; e += 256) atomicAdd(&lh[col[e] >> SH], 1);
    __syncthreads();
    for (int i = threadIdx.x; i < NB_BKT; i += 256) {
        int v = lh[i];
        lbase[i] = v ? atomicAdd(&bcur[i], v) : 0;
        lh[i] = 0;
    }
    __syncthreads();
    for (int e = base + threadIdx.x; e < end; e += 256) {
        int c = col[e];
        int r = row[e];
        int b = c >> SH;
        int off = atomicAdd(&lh[b], 1);
        packed[lbase[b] + off] = ((unsigned long long)(unsigned)c << 32) | (unsigned)r;
    }
}

// Fused: per-bucket degree count -> scan -> rowptr/self/dinv -> edge placement.
__global__ void bucket_nodes_place(const unsigned long long* __restrict__ packed,
                                   const int* __restrict__ bptr, int* __restrict__ rowptr,
                                   float* __restrict__ dinv, int* __restrict__ csr_row, int N) {
    int b = blockIdx.x;
    __shared__ int lcnt[128];
    __shared__ int lcur[128];
    __shared__ int wt4[4];
    int t = threadIdx.x;
    if (t < 128) lcnt[t] = 0;
    __syncthreads();
    int s = bptr[b], e = bptr[b + 1];
    for (int i = s + t; i < e; i += 256)
        atomicAdd(&lcnt[(int)(packed[i] >> 32) & 127], 1);
    __syncthreads();
    int node = (b << SH) + t;
    int v = (t < 128 && node < N) ? lcnt[t] + 1 : 0;   // +1 = self-edge slot
    int lane = t & 63, w = t >> 6;
    int incl = v;
#pragma unroll
    for (int off = 1; off < 64; off <<= 1) {
        int u = __shfl_up(incl, off, 64);
        if (lane >= off) incl += u;
    }
    if (lane == 63) wt4[w] = incl;
    __syncthreads();
    int woff = 0;
    for (int i = 0; i < w; i++) woff += wt4[i];
    int excl = woff + incl - v;
    if (t < 128 && node < N) {
        int start = bptr[b] + (b << SH) + excl;
        rowptr[node] = start;
        csr_row[start] = node;       // self edge first in segment
        dinv[node] = rsqrtf((float)v);
        lcur[t] = start + 1;
    }
    if (b == 0 && t == 0) rowptr[N] = NE + NN;
    __syncthreads();
    for (int i = s + t; i < e; i += 256) {   // packed range is L2-warm
        unsigned long long p = packed[i];
        int c = (int)(p >> 32);
        int r = (int)(p & 0xffffffffu);
        int pos = atomicAdd(&lcur[c & 127], 1);
        csr_row[pos] = r;
    }
}

// ======================= x pad copy (21 -> stride 32, zero pad) ==========
__global__ void padx_kernel(const float* __restrict__ x, float* __restrict__ xp, int N) {
    int idx = blockIdx.x * blockDim.x + threadIdx.x;
    if (idx >= N * 32) return;
    int n = idx >> 5;
    int k = idx & 31;
    xp[idx] = (k < 21) ? x[n * 21 + k] : 0.f;
}

// ======================= fused gather + GEMM (L1, L2) ====================
// Bank-check: L1 (JG=8,RJ=4): jg*4 spans banks 0..28 distinct -> conflict-free.
// L2 (JG=8,RJ=8): jg*8 mod 32 -> jg,jg+4 pair = 2-way = free (m136).
template <int LPN, int FIN, int FOUT, int RJ, int OSTRIDE>
__global__ __launch_bounds__(512) void gather_gemm(
    const float4* __restrict__ h, const int* __restrict__ rowptr,
    const int* __restrict__ csr_row, const float* __restrict__ dinv,
    const float* __restrict__ W, const float* __restrict__ b,
    float* __restrict__ out, int N) {
    constexpr int NT = 512 / LPN;        // nodes per block
    constexpr int FINP = 4 * LPN;        // gathered row width (>= FIN)
    constexpr int XLD = FINP + 1;
    constexpr int JG = FOUT / RJ;        // must satisfy 512/JG == NT
    __shared__ float xs[NT * XLD];
    __shared__ float Ws[FIN * FOUT];
    __shared__ float bs[FOUT];
    const int t = threadIdx.x;

    for (int i = t; i < FIN * FOUT; i += 512) Ws[i] = W[i];
    if (t < FOUT) bs[t] = b[t];

    // ---- gather phase ----
    const int l = t % LPN;
    const int ny = t / LPN;
    const int node = blockIdx.x * NT + ny;
    float4 acc = make_float4(0.f, 0.f, 0.f, 0.f);
    if (node < N) {
        int s = rowptr[node], e = rowptr[node + 1];
        float dn = dinv[node];
        int i = s;
        for (; i + 3 < e; i += 4) {
            int r0 = csr_row[i], r1 = csr_row[i + 1], r2 = csr_row[i + 2], r3 = csr_row[i + 3];
            float w0 = dinv[r0] * dn, w1 = dinv[r1] * dn, w2 = dinv[r2] * dn, w3 = dinv[r3] * dn;
            float4 a0 = h[(size_t)r0 * LPN + l];
            float4 a1 = h[(size_t)r1 * LPN + l];
            float4 a2 = h[(size_t)r2 * LPN + l];
            float4 a3 = h[(size_t)r3 * LPN + l];
            acc.x = fmaf(w0, a0.x, acc.x); acc.y = fmaf(w0, a0.y, acc.y);
            acc.z = fmaf(w0, a0.z, acc.z); acc.w = fmaf(w0, a0.w, acc.w);
            acc.x = fmaf(w1, a1.x, acc.x); acc.y = fmaf(w1, a1.y, acc.y);
            acc.z = fmaf(w1, a1.z, acc.z); acc.w = fmaf(w1, a1.w, acc.w);
            acc.x = fmaf(w2, a2.x, acc.x); acc.y = fmaf(w2, a2.y, acc.y);
            acc.z = fmaf(w2, a2.z, acc.z); acc.w = fmaf(w2, a2.w, acc.w);
            acc.x = fmaf(w3, a3.x, acc.x); acc.y = fmaf(w3, a3.y, acc.y);
            acc.z = fmaf(w3, a3.z, acc.z); acc.w = fmaf(w3, a3.w, acc.w);
        }
        for (; i < e; i++) {
            int r0 = csr_row[i];
            float w0 = dinv[r0] * dn;
            float4 a0 = h[(size_t)r0 * LPN + l];
            acc.x = fmaf(w0, a0.x, acc.x); acc.y = fmaf(w0, a0.y, acc.y);
            acc.z = fmaf(w0, a0.z, acc.z); acc.w = fmaf(w0, a0.w, acc.w);
        }
    }
    xs[ny * XLD + 4 * l + 0] = acc.x;
    xs[ny * XLD + 4 * l + 1] = acc.y;
    xs[ny * XLD + 4 * l + 2] = acc.z;
    xs[ny * XLD + 4 * l + 3] = acc.w;
    __syncthreads();

    // ---- GEMM phase ----
    const int jg = t % JG;
    const int ng = t / JG;
    float r[RJ];
#pragma unroll
    for (int jj = 0; jj < RJ; jj++) r[jj] = 0.f;
#pragma unroll 4
    for (int k = 0; k < FIN; k++) {
        float xv = xs[ng * XLD + k];
#pragma unroll
        for (int jj = 0; jj < RJ; jj++)
            r[jj] = fmaf(xv, Ws[k * FOUT + jg * RJ + jj], r[jj]);
    }
    int onode = blockIdx.x * NT + ng;
    if (onode < N) {
        float* orow = out + (size_t)onode * OSTRIDE + jg * RJ;
#pragma unroll
        for (int jj = 0; jj < RJ; jj++) r[jj] = fmaxf(r[jj] + bs[jg * RJ + jj], 0.f);
#pragma unroll
        for (int c = 0; c < RJ / 4; c++)
            *(float4*)&orow[4 * c] = make_float4(r[4 * c], r[4 * c + 1], r[4 * c + 2], r[4 * c + 3]);
    }
}

// ======================= standalone gather ===============================
template <int LPN, bool BIAS, bool STORE21>
__global__ void gather4_kernel(const float4* __restrict__ h, const int* __restrict__ rowptr,
                               const int* __restrict__ csr_row, const float* __restrict__ dinv,
                               const float* __restrict__ bias, float* __restrict__ outp, int N) {
    int node = blockIdx.x * blockDim.y + threadIdx.y;
    if (node >= N) return;
    int l = threadIdx.x;
    int s = rowptr[node], e = rowptr[node + 1];
    float dn = dinv[node];
    float4 acc = make_float4(0.f, 0.f, 0.f, 0.f);
    int i = s;
    for (; i + 3 < e; i += 4) {
        int r0 = csr_row[i], r1 = csr_row[i + 1], r2 = csr_row[i + 2], r3 = csr_row[i + 3];
        float w0 = dinv[r0] * dn, w1 = dinv[r1] * dn, w2 = dinv[r2] * dn, w3 = dinv[r3] * dn;
        float4 a0 = h[(size_t)r0 * LPN + l];
        float4 a1 = h[(size_t)r1 * LPN + l];
        float4 a2 = h[(size_t)r2 * LPN + l];
        float4 a3 = h[(size_t)r3 * LPN + l];
        acc.x = fmaf(w0, a0.x, acc.x); acc.y = fmaf(w0, a0.y, acc.y);
        acc.z = fmaf(w0, a0.z, acc.z); acc.w = fmaf(w0, a0.w, acc.w);
        acc.x = fmaf(w1, a1.x, acc.x); acc.y = fmaf(w1, a1.y, acc.y);
        acc.z = fmaf(w1, a1.z, acc.z); acc.w = fmaf(w1, a1.w, acc.w);
        acc.x = fmaf(w2, a2.x, acc.x); acc.y = fmaf(w2, a2.y, acc.y);
        acc.z = fmaf(w2, a2.z, acc.z); acc.w = fmaf(w2, a2.w, acc.w);
        acc.x = fmaf(w3, a3.x, acc.x); acc.y = fmaf(w3, a3.y, acc.y);
        acc.z = fmaf(w3, a3.z, acc.z); acc.w = fmaf(w3, a3.w, acc.w);
    }
    for (; i < e; i++) {
        int r0 = csr_row[i];
        float w0 = dinv[r0] * dn;
        float4 a0 = h[(size_t)r0 * LPN + l];
        acc.x = fmaf(w0, a0.x, acc.x); acc.y = fmaf(w0, a0.y, acc.y);
        acc.z = fmaf(w0, a0.z, acc.z); acc.w = fmaf(w0, a0.w, acc.w);
    }
    if (STORE21) {
        int j = 4 * l;
        float v[4] = {acc.x, acc.y, acc.z, acc.w};
#pragma unroll
        for (int c = 0; c < 4; c++) {
            int jj = j + c;
            if (jj < 21) outp[(size_t)node * 21 + jj] = v[c] + (BIAS ? bias[jj] : 0.f);
        }
    } else {
        ((float4*)outp)[(size_t)node * LPN + l] = acc;
    }
}

// ======================= fused L3+L4 GEMM (v2) ===========================
// agg (stride 64) -> h3 = relu(agg*W3+b3) in REGISTERS -> h4 = h3*W4 -> out
// (21 cols + 3 zero-pad, stride 32). 32 nodes/block, 256 threads.
// W3v interleaved float4: chunk k*32 + c*8 + jg = W3[k][jg*16+4c..+3]
//   -> lane jg reads banks 4jg..4jg+3: conflict-free.
// W4v interleaved float4: chunk i*48 + jq*8 + jg = W4[jg*16+i][4jq..+3] (0-pad j>=21)
//   -> banks 4jg..4jg+3: conflict-free.
// Phase-2 partials butterfly-reduced over the 8 contiguous jg lanes.
// LDS = 32K + 12K + 0.5K = 44.5KB -> 3 blocks/CU.
__global__ __launch_bounds__(256, 3) void gemm_l3l4(
    const float* __restrict__ agg, const float* __restrict__ W3,
    const float* __restrict__ b3, const float* __restrict__ W4,
    float* __restrict__ out, int N) {
    __shared__ float4 W3v[64 * 32];
    __shared__ float4 W4v[16 * 48];
    __shared__ float b3s[128];
    const int t = threadIdx.x;
    const int node0 = blockIdx.x * 32;

    // stage W3 (coalesced global read, permuted LDS write)
    for (int sid = t; sid < 64 * 32; sid += 256) {
        int k = sid >> 5, q = sid & 31;            // q = src col/4
        int jg = q >> 2, c = q & 3;
        W3v[(k << 5) + (c << 3) + jg] = ((const float4*)W3)[sid];
    }
    // stage W4 with zero pad
    for (int cid = t; cid < 16 * 48; cid += 256) {
        int i = cid / 48, rem = cid - i * 48;
        int jq = rem >> 3, jg = rem & 7;
        int k = jg * 16 + i;
        float v0 = (4 * jq + 0 < 21) ? W4[k * 21 + 4 * jq + 0] : 0.f;
        float v1 = (4 * jq + 1 < 21) ? W4[k * 21 + 4 * jq + 1] : 0.f;
        float v2 = (4 * jq + 2 < 21) ? W4[k * 21 + 4 * jq + 2] : 0.f;
        float v3 = (4 * jq + 3 < 21) ? W4[k * 21 + 4 * jq + 3] : 0.f;
        W4v[cid] = make_float4(v0, v1, v2, v3);
    }
    if (t < 128) b3s[t] = b3[t];
    __syncthreads();

    const int jg = t & 7;
    const int ng = t >> 3;
    const int node = node0 + ng;
    const float* arow = agg + (size_t)(node < N ? node : N - 1) * 64;

    // phase 1: acc[jj] = h3[node][jg*16+jj]
    float acc[16];
#pragma unroll
    for (int jj = 0; jj < 16; jj++) acc[jj] = 0.f;
#pragma unroll 4
    for (int k = 0; k < 64; k++) {
        float xv = arow[k];                        // 8 lanes same addr -> broadcast
        const float4* wb = &W3v[(k << 5) + jg];
#pragma unroll
        for (int c = 0; c < 4; c++) {
            float4 w = wb[c << 3];
            acc[4 * c + 0] = fmaf(xv, w.x, acc[4 * c + 0]);
            acc[4 * c + 1] = fmaf(xv, w.y, acc[4 * c + 1]);
            acc[4 * c + 2] = fmaf(xv, w.z, acc[4 * c + 2]);
            acc[4 * c + 3] = fmaf(xv, w.w, acc[4 * c + 3]);
        }
    }
#pragma unroll
    for (int jj = 0; jj < 16; jj++)
        acc[jj] = fmaxf(acc[jj] + b3s[jg * 16 + jj], 0.f);

    // phase 2: partials over this thread's k-range (jg*16 .. jg*16+15)
    float p[24];
#pragma unroll
    for (int j = 0; j < 24; j++) p[j] = 0.f;
#pragma unroll
    for (int i = 0; i < 16; i++) {
        float hv = acc[i];
        const float4* wb = &W4v[i * 48 + jg];
#pragma unroll
        for (int jq = 0; jq < 6; jq++) {
            float4 w = wb[jq << 3];
            p[4 * jq + 0] = fmaf(hv, w.x, p[4 * jq + 0]);
            p[4 * jq + 1] = fmaf(hv, w.y, p[4 * jq + 1]);
            p[4 * jq + 2] = fmaf(hv, w.z, p[4 * jq + 2]);
            p[4 * jq + 3] = fmaf(hv, w.w, p[4 * jq + 3]);
        }
    }
    // butterfly across the 8 jg lanes (contiguous within wave)
#pragma unroll
    for (int m = 1; m < 8; m <<= 1) {
#pragma unroll
        for (int j = 0; j < 24; j++) p[j] += __shfl_xor(p[j], m, 8);
    }
    if (node < N) {
        float* orow = out + (size_t)node * 32 + jg * 3;
        orow[0] = p[jg * 3 + 0];
        orow[1] = p[jg * 3 + 1];
        orow[2] = p[jg * 3 + 2];
    }
}

// ======================= launch ==========================================
extern "C" void kernel_launch(void* const* d_in, const int* in_sizes, int n_in,
                              void* d_out, int out_size, void* d_ws, size_t ws_size,
                              hipStream_t stream) {
    const float* x  = (const float*)d_in[0];
    const int*   ei = (const int*)d_in[1];
    const float* W1 = (const float*)d_in[2]; const float* b1 = (const float*)d_in[3];
    const float* W2 = (const float*)d_in[4]; const float* b2 = (const float*)d_in[5];
    const float* W3 = (const float*)d_in[6]; const float* b3 = (const float*)d_in[7];
    const float* W4 = (const float*)d_in[8]; const float* b4 = (const float*)d_in[9];
    const int* row = ei;
    const int* col = ei + NE;
    float* out = (float*)d_out;

    // workspace layout (floats)
    float* A      = (float*)d_ws;                  // N x 128
    float* B      = A + (size_t)NN * 128;          // N x 128
    float* dinv   = B + (size_t)NN * 128;          // N
    int*   rowptr = (int*)(dinv + NN);             // N+1
    int*   csr_row= rowptr + NN + 1;               // E + N
    int*   bcnt   = csr_row + NE + NN;             // NB_BKT
    int*   bptr   = bcnt + NB_BKT;                 // NB_BKT+1
    int*   bcur   = bptr + NB_BKT + 1;             // NB_BKT
    // packed (col,row) u64 aliases A: dead before layer-1 writes A
    unsigned long long* packed = (unsigned long long*)A;

    const int BS = 256;
    const int NCH = cdiv(NE, CHUNK);    // 196

    // ---- bucketed CSR build (5 dispatches) ----
    hipMemsetAsync(bcnt, 0, NB_BKT * sizeof(int), stream);
    bucket_hist<<<NCH, 256, 0, stream>>>(col, bcnt, NE);
    bucket_scan<<<1, 256, 0, stream>>>(bcnt, bptr, bcur);
    partition_kernel<<<NCH, 256, 0, stream>>>(row, col, bcur, packed, NE);
    bucket_nodes_place<<<NB_BKT, 256, 0, stream>>>(packed, bptr, rowptr, dinv, csr_row, NN);

    // ---- pad x into B (stride 32, zero-padded) ----
    padx_kernel<<<cdiv((long long)NN * 32, BS), BS, 0, stream>>>(x, B, NN);

    // ---- L1: fused gather(x32)+gemm 21->32 +b relu : B -> A (stride 32) ----
    gather_gemm<8, 21, 32, 4, 32><<<cdiv(NN, 64), 512, 0, stream>>>(
        (const float4*)B, rowptr, csr_row, dinv, W1, b1, A, NN);
    // ---- L2: fused gather(h1)+gemm 32->64 +b relu : A -> B (stride 64) ----
    gather_gemm<8, 32, 64, 8, 64><<<cdiv(NN, 64), 512, 0, stream>>>(
        (const float4*)A, rowptr, csr_row, dinv, W2, b2, B, NN);
    // ---- L3 gather: B -> A (stride 64) ----
    {
        dim3 blk(16, 16);
        gather4_kernel<16, false, false><<<cdiv(NN, 16), blk, 0, stream>>>(
            (const float4*)B, rowptr, csr_row, dinv, nullptr, A, NN);
    }
    // ---- fused L3+L4 GEMM: A -> B (h4, stride 32) ----
    gemm_l3l4<<<cdiv(NN, 32), 256, 0, stream>>>(A, W3, b3, W4, B, NN);
    // ---- L4 gather + b4: B -> out (stride 21) ----
    {
        dim3 blk(8, 32);
        gather4_kernel<8, true, true><<<cdiv(NN, 32), blk, 0, stream>>>(
            (const float4*)B, rowptr, csr_row, dinv, b4, out, NN);
    }
}

// Round 10
// 359.484 us; speedup vs baseline: 1.1392x; 1.0373x over previous
//
#include <hip/hip_runtime.h>

#define NN 100000
#define NE 1600000
#define SH 7
#define NB_BKT 782        // ceil(100000/128)
#define CHUNK 8192

static inline int cdiv(long long a, int b) { return (int)((a + b - 1) / b); }

// ======================= bucketed CSR build ==============================
__global__ void bucket_hist(const int* __restrict__ col, int* __restrict__ bcnt, int E) {
    __shared__ int lh[NB_BKT];
    for (int i = threadIdx.x; i < NB_BKT; i += 256) lh[i] = 0;
    __syncthreads();
    int base = blockIdx.x * CHUNK;
    int end = min(base + CHUNK, E);
    for (int e = base + threadIdx.x; e < end; e += 256) atomicAdd(&lh[col[e] >> SH], 1);
    __syncthreads();
    for (int i = threadIdx.x; i < NB_BKT; i += 256)
        if (lh[i]) atomicAdd(&bcnt[i], lh[i]);
}

__global__ void bucket_scan(const int* __restrict__ bcnt, int* __restrict__ bptr,
                            int* __restrict__ bcur) {
    int t = threadIdx.x;
    int v[4];
    int base = 4 * t;
    int s = 0;
#pragma unroll
    for (int c = 0; c < 4; c++) {
        int i = base + c;
        v[c] = (i < NB_BKT) ? bcnt[i] : 0;
        s += v[c];
    }
    int lane = t & 63, wv = t >> 6;
    int incl = s;
#pragma unroll
    for (int off = 1; off < 64; off <<= 1) {
        int u = __shfl_up(incl, off, 64);
        if (lane >= off) incl += u;
    }
    __shared__ int wtot[4];
    if (lane == 63) wtot[wv] = incl;
    __syncthreads();
    int woff = 0;
    for (int w = 0; w < wv; w++) woff += wtot[w];
    int excl = woff + incl - s;
#pragma unroll
    for (int c = 0; c < 4; c++) {
        int i = base + c;
        if (i < NB_BKT) { bptr[i] = excl; bcur[i] = excl; }
        excl += v[c];
    }
    if (t == 255) bptr[NB_BKT] = woff + incl;
}

__global__ void partition_kernel(const int* __restrict__ row, const int* __restrict__ col,
                                 int* __restrict__ bcur,
                                 unsigned long long* __restrict__ packed, int E) {
    __shared__ int lh[NB_BKT];
    __shared__ int lbase[NB_BKT];
    for (int i = threadIdx.x; i < NB_BKT; i += 256) lh[i] = 0;
    __syncthreads();
    int base = blockIdx.x * CHUNK;
    int end = min(base + CHUNK, E);
    for (int e = base + threadIdx.x; e < end; e += 256) atomicAdd(&lh[col[e] >> SH], 1);
    __syncthreads();
    for (int i = threadIdx.x; i < NB_BKT; i += 256) {
        int v = lh[i];
        lbase[i] = v ? atomicAdd(&bcur[i], v) : 0;
        lh[i] = 0;
    }
    __syncthreads();
    for (int e = base + threadIdx.x; e < end; e += 256) {
        int c = col[e];
        int r = row[e];
        int b = c >> SH;
        int off = atomicAdd(&lh[b], 1);
        packed[lbase[b] + off] = ((unsigned long long)(unsigned)c << 32) | (unsigned)r;
    }
}

// Fused: per-bucket degree count -> scan -> rowptr/self/dinv -> edge placement.
__global__ void bucket_nodes_place(const unsigned long long* __restrict__ packed,
                                   const int* __restrict__ bptr, int* __restrict__ rowptr,
                                   float* __restrict__ dinv, int* __restrict__ csr_row, int N) {
    int b = blockIdx.x;
    __shared__ int lcnt[128];
    __shared__ int lcur[128];
    __shared__ int wt4[4];
    int t = threadIdx.x;
    if (t < 128) lcnt[t] = 0;
    __syncthreads();
    int s = bptr[b], e = bptr[b + 1];
    for (int i = s + t; i < e; i += 256)
        atomicAdd(&lcnt[(int)(packed[i] >> 32) & 127], 1);
    __syncthreads();
    int node = (b << SH) + t;
    int v = (t < 128 && node < N) ? lcnt[t] + 1 : 0;   // +1 = self-edge slot
    int lane = t & 63, w = t >> 6;
    int incl = v;
#pragma unroll
    for (int off = 1; off < 64; off <<= 1) {
        int u = __shfl_up(incl, off, 64);
        if (lane >= off) incl += u;
    }
    if (lane == 63) wt4[w] = incl;
    __syncthreads();
    int woff = 0;
    for (int i = 0; i < w; i++) woff += wt4[i];
    int excl = woff + incl - v;
    if (t < 128 && node < N) {
        int start = bptr[b] + (b << SH) + excl;
        rowptr[node] = start;
        csr_row[start] = node;       // self edge first in segment
        dinv[node] = rsqrtf((float)v);
        lcur[t] = start + 1;
    }
    if (b == 0 && t == 0) rowptr[N] = NE + NN;
    __syncthreads();
    for (int i = s + t; i < e; i += 256) {   // packed range is L2-warm
        unsigned long long p = packed[i];
        int c = (int)(p >> 32);
        int r = (int)(p & 0xffffffffu);
        int pos = atomicAdd(&lcur[c & 127], 1);
        csr_row[pos] = r;
    }
}

// ======================= x pad copy (21 -> stride 32, zero pad) ==========
__global__ void padx_kernel(const float* __restrict__ x, float* __restrict__ xp, int N) {
    int idx = blockIdx.x * blockDim.x + threadIdx.x;
    if (idx >= N * 32) return;
    int n = idx >> 5;
    int k = idx & 31;
    xp[idx] = (k < 21) ? x[n * 21 + k] : 0.f;
}

// ======================= fused gather + GEMM (L1, L2) ====================
// Bank-check: L1 (JG=8,RJ=4): jg*4 spans banks 0..28 distinct -> conflict-free.
// L2 (JG=8,RJ=8): jg*8 mod 32 -> jg,jg+4 pair = 2-way = free (m136).
template <int LPN, int FIN, int FOUT, int RJ, int OSTRIDE>
__global__ __launch_bounds__(512) void gather_gemm(
    const float4* __restrict__ h, const int* __restrict__ rowptr,
    const int* __restrict__ csr_row, const float* __restrict__ dinv,
    const float* __restrict__ W, const float* __restrict__ b,
    float* __restrict__ out, int N) {
    constexpr int NT = 512 / LPN;        // nodes per block
    constexpr int FINP = 4 * LPN;        // gathered row width (>= FIN)
    constexpr int XLD = FINP + 1;
    constexpr int JG = FOUT / RJ;        // must satisfy 512/JG == NT
    __shared__ float xs[NT * XLD];
    __shared__ float Ws[FIN * FOUT];
    __shared__ float bs[FOUT];
    const int t = threadIdx.x;

    for (int i = t; i < FIN * FOUT; i += 512) Ws[i] = W[i];
    if (t < FOUT) bs[t] = b[t];

    // ---- gather phase ----
    const int l = t % LPN;
    const int ny = t / LPN;
    const int node = blockIdx.x * NT + ny;
    float4 acc = make_float4(0.f, 0.f, 0.f, 0.f);
    if (node < N) {
        int s = rowptr[node], e = rowptr[node + 1];
        float dn = dinv[node];
        int i = s;
        for (; i + 3 < e; i += 4) {
            int r0 = csr_row[i], r1 = csr_row[i + 1], r2 = csr_row[i + 2], r3 = csr_row[i + 3];
            float w0 = dinv[r0] * dn, w1 = dinv[r1] * dn, w2 = dinv[r2] * dn, w3 = dinv[r3] * dn;
            float4 a0 = h[(size_t)r0 * LPN + l];
            float4 a1 = h[(size_t)r1 * LPN + l];
            float4 a2 = h[(size_t)r2 * LPN + l];
            float4 a3 = h[(size_t)r3 * LPN + l];
            acc.x = fmaf(w0, a0.x, acc.x); acc.y = fmaf(w0, a0.y, acc.y);
            acc.z = fmaf(w0, a0.z, acc.z); acc.w = fmaf(w0, a0.w, acc.w);
            acc.x = fmaf(w1, a1.x, acc.x); acc.y = fmaf(w1, a1.y, acc.y);
            acc.z = fmaf(w1, a1.z, acc.z); acc.w = fmaf(w1, a1.w, acc.w);
            acc.x = fmaf(w2, a2.x, acc.x); acc.y = fmaf(w2, a2.y, acc.y);
            acc.z = fmaf(w2, a2.z, acc.z); acc.w = fmaf(w2, a2.w, acc.w);
            acc.x = fmaf(w3, a3.x, acc.x); acc.y = fmaf(w3, a3.y, acc.y);
            acc.z = fmaf(w3, a3.z, acc.z); acc.w = fmaf(w3, a3.w, acc.w);
        }
        for (; i < e; i++) {
            int r0 = csr_row[i];
            float w0 = dinv[r0] * dn;
            float4 a0 = h[(size_t)r0 * LPN + l];
            acc.x = fmaf(w0, a0.x, acc.x); acc.y = fmaf(w0, a0.y, acc.y);
            acc.z = fmaf(w0, a0.z, acc.z); acc.w = fmaf(w0, a0.w, acc.w);
        }
    }
    xs[ny * XLD + 4 * l + 0] = acc.x;
    xs[ny * XLD + 4 * l + 1] = acc.y;
    xs[ny * XLD + 4 * l + 2] = acc.z;
    xs[ny * XLD + 4 * l + 3] = acc.w;
    __syncthreads();

    // ---- GEMM phase ----
    const int jg = t % JG;
    const int ng = t / JG;
    float r[RJ];
#pragma unroll
    for (int jj = 0; jj < RJ; jj++) r[jj] = 0.f;
#pragma unroll 4
    for (int k = 0; k < FIN; k++) {
        float xv = xs[ng * XLD + k];
#pragma unroll
        for (int jj = 0; jj < RJ; jj++)
            r[jj] = fmaf(xv, Ws[k * FOUT + jg * RJ + jj], r[jj]);
    }
    int onode = blockIdx.x * NT + ng;
    if (onode < N) {
        float* orow = out + (size_t)onode * OSTRIDE + jg * RJ;
#pragma unroll
        for (int jj = 0; jj < RJ; jj++) r[jj] = fmaxf(r[jj] + bs[jg * RJ + jj], 0.f);
#pragma unroll
        for (int c = 0; c < RJ / 4; c++)
            *(float4*)&orow[4 * c] = make_float4(r[4 * c], r[4 * c + 1], r[4 * c + 2], r[4 * c + 3]);
    }
}

// ======================= standalone gather ===============================
template <int LPN, bool BIAS, bool STORE21>
__global__ void gather4_kernel(const float4* __restrict__ h, const int* __restrict__ rowptr,
                               const int* __restrict__ csr_row, const float* __restrict__ dinv,
                               const float* __restrict__ bias, float* __restrict__ outp, int N) {
    int node = blockIdx.x * blockDim.y + threadIdx.y;
    if (node >= N) return;
    int l = threadIdx.x;
    int s = rowptr[node], e = rowptr[node + 1];
    float dn = dinv[node];
    float4 acc = make_float4(0.f, 0.f, 0.f, 0.f);
    int i = s;
    for (; i + 3 < e; i += 4) {
        int r0 = csr_row[i], r1 = csr_row[i + 1], r2 = csr_row[i + 2], r3 = csr_row[i + 3];
        float w0 = dinv[r0] * dn, w1 = dinv[r1] * dn, w2 = dinv[r2] * dn, w3 = dinv[r3] * dn;
        float4 a0 = h[(size_t)r0 * LPN + l];
        float4 a1 = h[(size_t)r1 * LPN + l];
        float4 a2 = h[(size_t)r2 * LPN + l];
        float4 a3 = h[(size_t)r3 * LPN + l];
        acc.x = fmaf(w0, a0.x, acc.x); acc.y = fmaf(w0, a0.y, acc.y);
        acc.z = fmaf(w0, a0.z, acc.z); acc.w = fmaf(w0, a0.w, acc.w);
        acc.x = fmaf(w1, a1.x, acc.x); acc.y = fmaf(w1, a1.y, acc.y);
        acc.z = fmaf(w1, a1.z, acc.z); acc.w = fmaf(w1, a1.w, acc.w);
        acc.x = fmaf(w2, a2.x, acc.x); acc.y = fmaf(w2, a2.y, acc.y);
        acc.z = fmaf(w2, a2.z, acc.z); acc.w = fmaf(w2, a2.w, acc.w);
        acc.x = fmaf(w3, a3.x, acc.x); acc.y = fmaf(w3, a3.y, acc.y);
        acc.z = fmaf(w3, a3.z, acc.z); acc.w = fmaf(w3, a3.w, acc.w);
    }
    for (; i < e; i++) {
        int r0 = csr_row[i];
        float w0 = dinv[r0] * dn;
        float4 a0 = h[(size_t)r0 * LPN + l];
        acc.x = fmaf(w0, a0.x, acc.x); acc.y = fmaf(w0, a0.y, acc.y);
        acc.z = fmaf(w0, a0.z, acc.z); acc.w = fmaf(w0, a0.w, acc.w);
    }
    if (STORE21) {
        int j = 4 * l;
        float v[4] = {acc.x, acc.y, acc.z, acc.w};
#pragma unroll
        for (int c = 0; c < 4; c++) {
            int jj = j + c;
            if (jj < 21) outp[(size_t)node * 21 + jj] = v[c] + (BIAS ? bias[jj] : 0.f);
        }
    } else {
        ((float4*)outp)[(size_t)node * LPN + l] = acc;
    }
}

// ======================= fused L3+L4 GEMM (v3: RN=2) =====================
// agg (stride 64) -> h3 = relu(agg*W3+b3) in REGISTERS -> h4 = h3*W4 -> out
// (21 cols + 3 zero-pad, stride 32). 64 nodes/block (2 per thread), 256 thr.
// One W LDS-read feeds 2 nodes' FMAs -> LDS read bytes/FLOP halved vs v2
// (v2 was LDS-BW bound: 4.5 GB LDS reads = 57-86us floor, measured 69).
// W3v/W4v interleaved float4 layouts: lane jg reads banks 4jg..4jg+3,
// conflict-free (verified r9: conflicts 1.44e7 -> 2.6e6, residual=staging).
__global__ __launch_bounds__(256, 3) void gemm_l3l4(
    const float* __restrict__ agg, const float* __restrict__ W3,
    const float* __restrict__ b3, const float* __restrict__ W4,
    float* __restrict__ out, int N) {
    __shared__ float4 W3v[64 * 32];
    __shared__ float4 W4v[16 * 48];
    __shared__ float b3s[128];
    const int t = threadIdx.x;
    const int node0 = blockIdx.x * 64;

    // stage W3 (coalesced global read, permuted LDS write)
    for (int sid = t; sid < 64 * 32; sid += 256) {
        int k = sid >> 5, q = sid & 31;            // q = src col/4
        int jg = q >> 2, c = q & 3;
        W3v[(k << 5) + (c << 3) + jg] = ((const float4*)W3)[sid];
    }
    // stage W4 with zero pad
    for (int cid = t; cid < 16 * 48; cid += 256) {
        int i = cid / 48, rem = cid - i * 48;
        int jq = rem >> 3, jg = rem & 7;
        int k = jg * 16 + i;
        float v0 = (4 * jq + 0 < 21) ? W4[k * 21 + 4 * jq + 0] : 0.f;
        float v1 = (4 * jq + 1 < 21) ? W4[k * 21 + 4 * jq + 1] : 0.f;
        float v2 = (4 * jq + 2 < 21) ? W4[k * 21 + 4 * jq + 2] : 0.f;
        float v3 = (4 * jq + 3 < 21) ? W4[k * 21 + 4 * jq + 3] : 0.f;
        W4v[cid] = make_float4(v0, v1, v2, v3);
    }
    if (t < 128) b3s[t] = b3[t];
    __syncthreads();

    const int jg = t & 7;
    const int ng = t >> 3;
    const int nodeA = node0 + ng;
    const int nodeB = node0 + 32 + ng;
    const float* arowA = agg + (size_t)(nodeA < N ? nodeA : N - 1) * 64;
    const float* arowB = agg + (size_t)(nodeB < N ? nodeB : N - 1) * 64;

    // phase 1: acc[n][jj] = h3[node_n][jg*16+jj]
    float accA[16], accB[16];
#pragma unroll
    for (int jj = 0; jj < 16; jj++) { accA[jj] = 0.f; accB[jj] = 0.f; }
#pragma unroll 4
    for (int k = 0; k < 64; k++) {
        float xa = arowA[k];                       // 8 lanes same addr -> broadcast
        float xb = arowB[k];
        const float4* wb = &W3v[(k << 5) + jg];
#pragma unroll
        for (int c = 0; c < 4; c++) {
            float4 w = wb[c << 3];
            accA[4 * c + 0] = fmaf(xa, w.x, accA[4 * c + 0]);
            accA[4 * c + 1] = fmaf(xa, w.y, accA[4 * c + 1]);
            accA[4 * c + 2] = fmaf(xa, w.z, accA[4 * c + 2]);
            accA[4 * c + 3] = fmaf(xa, w.w, accA[4 * c + 3]);
            accB[4 * c + 0] = fmaf(xb, w.x, accB[4 * c + 0]);
            accB[4 * c + 1] = fmaf(xb, w.y, accB[4 * c + 1]);
            accB[4 * c + 2] = fmaf(xb, w.z, accB[4 * c + 2]);
            accB[4 * c + 3] = fmaf(xb, w.w, accB[4 * c + 3]);
        }
    }
#pragma unroll
    for (int jj = 0; jj < 16; jj++) {
        float bb = b3s[jg * 16 + jj];
        accA[jj] = fmaxf(accA[jj] + bb, 0.f);
        accB[jj] = fmaxf(accB[jj] + bb, 0.f);
    }

    // phase 2: partials over this thread's k-range (jg*16 .. jg*16+15)
    float pA[24], pB[24];
#pragma unroll
    for (int j = 0; j < 24; j++) { pA[j] = 0.f; pB[j] = 0.f; }
#pragma unroll
    for (int i = 0; i < 16; i++) {
        float ha = accA[i];
        float hb = accB[i];
        const float4* wb = &W4v[i * 48 + jg];
#pragma unroll
        for (int jq = 0; jq < 6; jq++) {
            float4 w = wb[jq << 3];
            pA[4 * jq + 0] = fmaf(ha, w.x, pA[4 * jq + 0]);
            pA[4 * jq + 1] = fmaf(ha, w.y, pA[4 * jq + 1]);
            pA[4 * jq + 2] = fmaf(ha, w.z, pA[4 * jq + 2]);
            pA[4 * jq + 3] = fmaf(ha, w.w, pA[4 * jq + 3]);
            pB[4 * jq + 0] = fmaf(hb, w.x, pB[4 * jq + 0]);
            pB[4 * jq + 1] = fmaf(hb, w.y, pB[4 * jq + 1]);
            pB[4 * jq + 2] = fmaf(hb, w.z, pB[4 * jq + 2]);
            pB[4 * jq + 3] = fmaf(hb, w.w, pB[4 * jq + 3]);
        }
    }
    // butterfly across the 8 jg lanes (contiguous within wave)
#pragma unroll
    for (int m = 1; m < 8; m <<= 1) {
#pragma unroll
        for (int j = 0; j < 24; j++) {
            pA[j] += __shfl_xor(pA[j], m, 8);
            pB[j] += __shfl_xor(pB[j], m, 8);
        }
    }
    if (nodeA < N) {
        float* orow = out + (size_t)nodeA * 32 + jg * 3;
        orow[0] = pA[jg * 3 + 0];
        orow[1] = pA[jg * 3 + 1];
        orow[2] = pA[jg * 3 + 2];
    }
    if (nodeB < N) {
        float* orow = out + (size_t)nodeB * 32 + jg * 3;
        orow[0] = pB[jg * 3 + 0];
        orow[1] = pB[jg * 3 + 1];
        orow[2] = pB[jg * 3 + 2];
    }
}

// ======================= launch ==========================================
extern "C" void kernel_launch(void* const* d_in, const int* in_sizes, int n_in,
                              void* d_out, int out_size, void* d_ws, size_t ws_size,
                              hipStream_t stream) {
    const float* x  = (const float*)d_in[0];
    const int*   ei = (const int*)d_in[1];
    const float* W1 = (const float*)d_in[2]; const float* b1 = (const float*)d_in[3];
    const float* W2 = (const float*)d_in[4]; const float* b2 = (const float*)d_in[5];
    const float* W3 = (const float*)d_in[6]; const float* b3 = (const float*)d_in[7];
    const float* W4 = (const float*)d_in[8]; const float* b4 = (const float*)d_in[9];
    const int* row = ei;
    const int* col = ei + NE;
    float* out = (float*)d_out;

    // workspace layout (floats)
    float* A      = (float*)d_ws;                  // N x 128
    float* B      = A + (size_t)NN * 128;          // N x 128
    float* dinv   = B + (size_t)NN * 128;          // N
    int*   rowptr = (int*)(dinv + NN);             // N+1
    int*   csr_row= rowptr + NN + 1;               // E + N
    int*   bcnt   = csr_row + NE + NN;             // NB_BKT
    int*   bptr   = bcnt + NB_BKT;                 // NB_BKT+1
    int*   bcur   = bptr + NB_BKT + 1;             // NB_BKT
    // packed (col,row) u64 aliases A: dead before layer-1 writes A
    unsigned long long* packed = (unsigned long long*)A;

    const int BS = 256;
    const int NCH = cdiv(NE, CHUNK);    // 196

    // ---- bucketed CSR build (5 dispatches) ----
    hipMemsetAsync(bcnt, 0, NB_BKT * sizeof(int), stream);
    bucket_hist<<<NCH, 256, 0, stream>>>(col, bcnt, NE);
    bucket_scan<<<1, 256, 0, stream>>>(bcnt, bptr, bcur);
    partition_kernel<<<NCH, 256, 0, stream>>>(row, col, bcur, packed, NE);
    bucket_nodes_place<<<NB_BKT, 256, 0, stream>>>(packed, bptr, rowptr, dinv, csr_row, NN);

    // ---- pad x into B (stride 32, zero-padded) ----
    padx_kernel<<<cdiv((long long)NN * 32, BS), BS, 0, stream>>>(x, B, NN);

    // ---- L1: fused gather(x32)+gemm 21->32 +b relu : B -> A (stride 32) ----
    gather_gemm<8, 21, 32, 4, 32><<<cdiv(NN, 64), 512, 0, stream>>>(
        (const float4*)B, rowptr, csr_row, dinv, W1, b1, A, NN);
    // ---- L2: fused gather(h1)+gemm 32->64 +b relu : A -> B (stride 64) ----
    gather_gemm<8, 32, 64, 8, 64><<<cdiv(NN, 64), 512, 0, stream>>>(
        (const float4*)A, rowptr, csr_row, dinv, W2, b2, B, NN);
    // ---- L3 gather: B -> A (stride 64) ----
    {
        dim3 blk(16, 16);
        gather4_kernel<16, false, false><<<cdiv(NN, 16), blk, 0, stream>>>(
            (const float4*)B, rowptr, csr_row, dinv, nullptr, A, NN);
    }
    // ---- fused L3+L4 GEMM: A -> B (h4, stride 32) ----
    gemm_l3l4<<<cdiv(NN, 64), 256, 0, stream>>>(A, W3, b3, W4, B, NN);
    // ---- L4 gather + b4: B -> out (stride 21) ----
    {
        dim3 blk(8, 32);
        gather4_kernel<8, true, true><<<cdiv(NN, 32), blk, 0, stream>>>(
            (const float4*)B, rowptr, csr_row, dinv, b4, out, NN);
    }
}